// Round 10
// baseline (152.508 us; speedup 1.0000x reference)
//
#include <hip/hip_runtime.h>
#include <math.h>

#define NB   4
#define NSEQ 8192
#define CDIM 64
#define M    2048
#define NW   7
#define NBLK 80      // sub-blocks (qt,ci) per window: 8*1+8*2+8*3+8*4

typedef _Float16 half8 __attribute__((ext_vector_type(8)));
typedef __fp16 fp16x2 __attribute__((ext_vector_type(2)));   // native cvt_pkrtz type
typedef float f32x4 __attribute__((ext_vector_type(4)));
typedef unsigned short u16x4 __attribute__((ext_vector_type(4)));

#if defined(__has_builtin) && __has_builtin(__builtin_amdgcn_exp2f)
#define EXP2(x) __builtin_amdgcn_exp2f(x)
#else
#define EXP2(x) __expf((x) * 0.69314718056f)
#endif

// Q pre-scale: 1/sqrt(64) * log2(e) folded into Qg so attn uses raw exp2
#define QSCALE 0.1803368801111204f
// exp bias: p = exp2(s' - PBIAS) keeps P under f16 max; scales P and l by
// 2^-PBIAS uniformly -> O invariant, constant lse shift cancels in mix.
#define PBIAS 4.0f

// LDS layout (23552 B total -> 6 blocks/CU; R9's 40KB capped at 4):
//   [0,8192):      K dbuf, 2 x 32 rows x 128B (R9 swizzle)
//   [8192,18432):  Vt dbuf, 2 x 64 rows x 80B pitch (pair-packed, padded)
//   [18432,23552): Ps, 64 rows x 80B pitch (pair-packed, padded)
#define K_OFF   0
#define VT_OFF  8192
#define PS_OFF  18432

__device__ __forceinline__ int win_base(int w) {
    return (w < 4) ? (w << 11) : ((w < 6) ? ((w - 4) << 12) : 0);
}
__device__ __forceinline__ int win_stride(int w) {
    return (w < 4) ? 1 : ((w < 6) ? 2 : 4);
}

// ---------------- kernel 1: QKV projection, f16 outputs -------------------
// block = 64 (1 wave): lane owns output column; W columns live in registers
// (192 VGPRs -> needs the 512-VGPR budget of launch_bounds(64,1); capping
// lower forces catastrophic scratch spills - measured 377MB FETCH in R3).
__global__ __launch_bounds__(64, 1) void qkv_proj(
        const float* __restrict__ x,
        const float* __restrict__ Wq, const float* __restrict__ Wk,
        const float* __restrict__ Wv,
        _Float16* __restrict__ Qg, _Float16* __restrict__ Kg,
        _Float16* __restrict__ Vg) {
    __shared__ __align__(16) float xs[32][64];
    const int lane = threadIdx.x;
    const long rowbase = (long)blockIdx.x * 32;

    float wq[64], wk[64], wv[64];
#pragma unroll
    for (int i = 0; i < 64; ++i) {
        wq[i] = Wq[i * 64 + lane];
        wk[i] = Wk[i * 64 + lane];
        wv[i] = Wv[i * 64 + lane];
    }
#pragma unroll
    for (int i = 0; i < 8; ++i) {
        int idx = lane + i * 64;            // 512 float4 chunks: 32 rows x 16
        int r = idx >> 4, ch = idx & 15;
        *(float4*)&xs[r][ch * 4] = *(const float4*)&x[(rowbase + r) * 64 + ch * 4];
    }
    __syncthreads();
    for (int r = 0; r < 32; ++r) {
        float aq = 0.f, ak = 0.f, av = 0.f;
#pragma unroll
        for (int i = 0; i < 64; i += 4) {
            float4 xv = *(const float4*)&xs[r][i];
            aq += xv.x * wq[i] + xv.y * wq[i + 1] + xv.z * wq[i + 2] + xv.w * wq[i + 3];
            ak += xv.x * wk[i] + xv.y * wk[i + 1] + xv.z * wk[i + 2] + xv.w * wk[i + 3];
            av += xv.x * wv[i] + xv.y * wv[i + 1] + xv.z * wv[i + 2] + xv.w * wv[i + 3];
        }
        long o = (rowbase + r) * 64 + lane;
        Qg[o] = (_Float16)(aq * QSCALE);
        Kg[o] = (_Float16)ak;
        Vg[o] = (_Float16)av;
    }
}

// ---------------- kernel 2: split-K MFMA flash attention, 32-row k-steps --
// block = (b, w, qt, ci); chunk = 512 k-columns = 16 steps of 32 rows.
// Same dbuf/prefetch/wave-private-P/heavy-first structure as R9, but k-step
// halved so LDS = 23.5KB -> 6 blocks/CU (R9: 40KB -> 4). Vt/Ps use pitch-80
// rows (conflict-free without swizzle) and (k,k+16) pair packing so P writes
// are packed b32 and the PV contraction order matches on both operands.
__global__ __launch_bounds__(256, 6) void attn(
        const _Float16* __restrict__ Qg, const _Float16* __restrict__ Kg,
        const _Float16* __restrict__ Vg,
        _Float16* __restrict__ Op, float* __restrict__ LSEp) {
    __shared__ __align__(16) char smem[23552];

    // decode (qt, ci) from reversed blockIdx.x in [0,80): heavy groups first
    int id = 79 - (int)blockIdx.x;
    int qt, ci;
    if (id < 8)       { qt = id;               ci = 0; }
    else if (id < 24) { int r = id - 8;  qt = 8  + (r >> 1); ci = r & 1; }
    else if (id < 48) { int r = id - 24; int q3 = r / 3; qt = 16 + q3; ci = r - 3 * q3; }
    else              { int r = id - 48; qt = 24 + (r >> 2); ci = r & 3; }
    const int w = blockIdx.y, b = blockIdx.z;
    const int base = win_base(w), stride = win_stride(w);
    const int g = qt >> 3;
    const int outblk = (b * NW + w) * NBLK + (g + 1) * (4 * g + (qt & 7)) + ci;
    const int kt0 = ci * 16;                 // 32-row steps
    const int ktmax = 2 * qt + 2;
    const int kt1 = (kt0 + 16 < ktmax) ? kt0 + 16 : ktmax;

    const _Float16* Qb = Qg + (size_t)b * NSEQ * 64;
    const _Float16* Kb = Kg + (size_t)b * NSEQ * 64;
    const _Float16* Vb = Vg + (size_t)b * NSEQ * 64;

    const int t = threadIdx.x;
    const int wid = t >> 6, lane = t & 63, l15 = lane & 15, quad = lane >> 4;

    // K staging: thread stages row sr (0..31), 16B chunk sch
    const int sr = t >> 3, sch = t & 7;
    // V staging: thread stages rows (kq, kq+16), 4 d-columns from d0
    const int kq = t & 15, d0 = (t >> 4) * 4;

    // Q A-frags: load once (A[m=l15][k=quad*8+j])
    const size_t qr = (size_t)(base + stride * (qt * 64 + 16 * wid + l15)) * 64;
    const half8 qa0 = *(const half8*)(Qb + qr + quad * 8);
    const half8 qa1 = *(const half8*)(Qb + qr + 32 + quad * 8);

    f32x4 oacc[4];
    float l_[4];
#pragma unroll
    for (int ns = 0; ns < 4; ++ns) oacc[ns] = (f32x4){0.f, 0.f, 0.f, 0.f};
#pragma unroll
    for (int j = 0; j < 4; ++j) l_[j] = 0.f;

    half8 pk;
    u16x4 pv0, pv1;

    // ---- prologue: stage step kt0 into buffer 0 ----
    {
        const size_t ka = (size_t)(base + stride * (kt0 * 32 + sr)) * 64 + sch * 8;
        pk = *(const half8*)(Kb + ka);
        const size_t va = (size_t)(base + stride * (kt0 * 32 + kq)) * 64 + d0;
        pv0 = *(const u16x4*)(Vb + va);
        pv1 = *(const u16x4*)(Vb + va + (size_t)stride * 16 * 64);
        char* Kd = smem + K_OFF;
        char* Vd = smem + VT_OFF;
        *(half8*)(Kd + sr * 128 + ((sch ^ (sr & 7)) * 16)) = pk;
#pragma unroll
        for (int i = 0; i < 4; ++i) {
            int d = d0 + i;
            unsigned int pkw = (unsigned int)pv0[i] | ((unsigned int)pv1[i] << 16);
            *(unsigned int*)(Vd + d * 80 + 4 * kq) = pkw;
        }
    }

    int cur = 0;
    for (int kt = kt0; kt < kt1; ++kt) {
        __syncthreads();   // buf[cur] visible; all reads of buf[cur^1] done
        const bool pf = (kt + 1 < kt1);
        if (pf) {   // prefetch next step (consumed at end of this iteration)
            const size_t ka = (size_t)(base + stride * ((kt + 1) * 32 + sr)) * 64 + sch * 8;
            pk = *(const half8*)(Kb + ka);
            const size_t va = (size_t)(base + stride * ((kt + 1) * 32 + kq)) * 64 + d0;
            pv0 = *(const u16x4*)(Vb + va);
            pv1 = *(const u16x4*)(Vb + va + (size_t)stride * 16 * 64);
        }

        const char* Kd = smem + K_OFF + cur * 4096;
        const char* Vd = smem + VT_OFF + cur * 5120;
        char* PsB = smem + PS_OFF;

        // ---- QK^T: S[64q x 32k] ----
        f32x4 sa[2];
#pragma unroll
        for (int ns = 0; ns < 2; ++ns) {
            const int krow = ns * 16 + l15, swk = krow & 7;
            half8 b0 = *(const half8*)(Kd + krow * 128 + ((quad ^ swk) * 16));
            half8 b1 = *(const half8*)(Kd + krow * 128 + (((quad + 4) ^ swk) * 16));
            f32x4 c = (f32x4){0.f, 0.f, 0.f, 0.f};
            c = __builtin_amdgcn_mfma_f32_16x16x32_f16(qa0, b0, c, 0, 0, 0);
            c = __builtin_amdgcn_mfma_f32_16x16x32_f16(qa1, b1, c, 0, 0, 0);
            sa[ns] = c;
        }
        if (kt >= 2 * qt) {   // causal mask (diagonal spans 2 k-steps)
            const int colb = kt * 32 + l15;
            const int row0 = qt * 64 + 16 * wid + quad * 4;
#pragma unroll
            for (int ns = 0; ns < 2; ++ns)
#pragma unroll
                for (int j = 0; j < 4; ++j)
                    if (colb + ns * 16 > row0 + j) sa[ns][j] = -1e30f;
        }

        // ---- exp2, l accum, P write: pair (k=l15, k=l15+16) -> one b32 ----
#pragma unroll
        for (int j = 0; j < 4; ++j) {
            const int q = 16 * wid + quad * 4 + j;
            float p0 = EXP2(sa[0][j] - PBIAS);
            float p1 = EXP2(sa[1][j] - PBIAS);
            l_[j] += p0 + p1;
            union { fp16x2 h; unsigned int u; } pw;
            pw.h = __builtin_amdgcn_cvt_pkrtz(p0, p1);
            *(unsigned int*)(PsB + q * 80 + 4 * l15) = pw.u;
        }

        // own-strip P A-frag (wave-private: no barrier needed)
        const int qp = 16 * wid + l15;
        half8 pa = *(const half8*)(PsB + qp * 80 + 16 * quad);

        // ---- PV: O[q][d] += P(A) * Vt(B), both in pair order ----
#pragma unroll
        for (int ns = 0; ns < 4; ++ns) {
            const int d = ns * 16 + l15;
            half8 vb = *(const half8*)(Vd + d * 80 + 16 * quad);
            oacc[ns] = __builtin_amdgcn_mfma_f32_16x16x32_f16(pa, vb, oacc[ns], 0, 0, 0);
        }

        // ---- write prefetched step into the other buffer ----
        if (pf) {
            char* Kn = smem + K_OFF + (cur ^ 1) * 4096;
            char* Vn = smem + VT_OFF + (cur ^ 1) * 5120;
            *(half8*)(Kn + sr * 128 + ((sch ^ (sr & 7)) * 16)) = pk;
#pragma unroll
            for (int i = 0; i < 4; ++i) {
                int d = d0 + i;
                unsigned int pkw = (unsigned int)pv0[i] | ((unsigned int)pv1[i] << 16);
                *(unsigned int*)(Vn + d * 80 + 4 * kq) = pkw;
            }
        }
        cur ^= 1;
    }

    // ---- epilogue: reduce l over the 16 lanes of each quad-row, store ----
#pragma unroll
    for (int j = 0; j < 4; ++j) {
        float s = l_[j];
        s += __shfl_xor(s, 1, 16);
        s += __shfl_xor(s, 2, 16);
        s += __shfl_xor(s, 4, 16);
        s += __shfl_xor(s, 8, 16);
        l_[j] = s;
    }
    const int qrow = 16 * wid + quad * 4;
    if (l15 == 0) {
#pragma unroll
        for (int j = 0; j < 4; ++j)
            LSEp[(size_t)outblk * 64 + qrow + j] = __logf(l_[j]);
    }
#pragma unroll
    for (int j = 0; j < 4; ++j) {
        const float inv = 1.0f / l_[j];
        const size_t rowoff = ((size_t)outblk * 64 + qrow + j) * 64 + l15;
#pragma unroll
        for (int ns = 0; ns < 4; ++ns)
            Op[rowoff + ns * 16] = (_Float16)(oacc[ns][j] * inv);
    }
}

// ---------------- kernel 3: merge all (window, chunk) partials ------------
typedef _Float16 half8v __attribute__((ext_vector_type(8)));
__global__ __launch_bounds__(256) void mix_out(
        const _Float16* __restrict__ Op, const float* __restrict__ LSEp,
        float* __restrict__ out) {
    int gid = blockIdx.x * 256 + threadIdx.x;   // [0, 4*8192*8)
    int f8 = gid & 7;
    int tpos = (gid >> 3) & (NSEQ - 1);
    int b = gid >> 16;

    int idxs[12];
    float lse[12];
    int nref = 0;
    {   // window of stride 1
        int w = tpos >> 11, j = tpos & (M - 1);
        int qt = j >> 6, gg = qt >> 3, q = j & 63;
        int bb = ((b * NW + w) * NBLK + (gg + 1) * (4 * gg + (qt & 7))) * 64 + q;
        for (int c = 0; c <= gg; ++c) { idxs[nref] = bb + c * 64; lse[nref] = LSEp[idxs[nref]]; ++nref; }
    }
    if (!(tpos & 1)) {   // stride 2
        int w = 4 + (tpos >> 12), j = (tpos & 4095) >> 1;
        int qt = j >> 6, gg = qt >> 3, q = j & 63;
        int bb = ((b * NW + w) * NBLK + (gg + 1) * (4 * gg + (qt & 7))) * 64 + q;
        for (int c = 0; c <= gg; ++c) { idxs[nref] = bb + c * 64; lse[nref] = LSEp[idxs[nref]]; ++nref; }
    }
    if (!(tpos & 3)) {   // stride 4
        int j = tpos >> 2;
        int qt = j >> 6, gg = qt >> 3, q = j & 63;
        int bb = ((b * NW + 6) * NBLK + (gg + 1) * (4 * gg + (qt & 7))) * 64 + q;
        for (int c = 0; c <= gg; ++c) { idxs[nref] = bb + c * 64; lse[nref] = LSEp[idxs[nref]]; ++nref; }
    }

    float Mx = -1e30f;
    for (int i = 0; i < nref; ++i) Mx = fmaxf(Mx, lse[i]);
    float acc[8];
#pragma unroll
    for (int k = 0; k < 8; ++k) acc[k] = 0.f;
    float wsum = 0.f;
    for (int i = 0; i < nref; ++i) {
        float a = __expf(lse[i] - Mx);
        wsum += a;
        half8v v = *(const half8v*)(Op + (size_t)idxs[i] * 64 + f8 * 8);
#pragma unroll
        for (int k = 0; k < 8; ++k) acc[k] += a * (float)v[k];
    }
    float inv = 1.0f / wsum;
    size_t o = ((size_t)b * NSEQ + tpos) * 64 + f8 * 8;
    float4 r0 = make_float4(acc[0] * inv, acc[1] * inv, acc[2] * inv, acc[3] * inv);
    float4 r1 = make_float4(acc[4] * inv, acc[5] * inv, acc[6] * inv, acc[7] * inv);
    *(float4*)&out[o] = r0;
    *(float4*)&out[o + 4] = r1;
}

extern "C" void kernel_launch(void* const* d_in, const int* in_sizes, int n_in,
                              void* d_out, int out_size, void* d_ws, size_t ws_size,
                              hipStream_t stream) {
    const float* x  = (const float*)d_in[0];
    const float* Wq = (const float*)d_in[1];
    const float* Wk = (const float*)d_in[2];
    const float* Wv = (const float*)d_in[3];
    float* out = (float*)d_out;

    const size_t QN = (size_t)NB * NSEQ * CDIM;     // 2,097,152
    _Float16* Qg = (_Float16*)d_ws;
    _Float16* Kg = Qg + QN;
    _Float16* Vg = Kg + QN;
    _Float16* Op = Vg + QN;                         // [b][w][80][64][64] f16
    float* LSEp  = (float*)(Op + (size_t)NB * NW * NBLK * 64 * 64);

    qkv_proj<<<NB * NSEQ / 32, 64, 0, stream>>>(x, Wq, Wk, Wv, Qg, Kg, Vg);
    attn<<<dim3(NBLK, NW, NB), 256, 0, stream>>>(Qg, Kg, Vg, Op, LSEp);
    mix_out<<<(NB * NSEQ * 8) / 256, 256, 0, stream>>>(Op, LSEp, out);
}